// Round 13
// baseline (70.095 us; speedup 1.0000x reference)
//
#include <hip/hip_runtime.h>
#include <math.h>

constexpr int H = 32, W = 32, C = 128, G = 4, K = 15, K2 = 225, GC = 32;
constexpr int NPIX = H * W;
constexpr int NOFF = G * K2 * 2;   // 1800
constexpr int NMSK = G * K2;       // 900
constexpr int NTOT = NOFF + NMSK;  // 2700
constexpr int KHID = 32;

// workspace layout (float offsets)
constexpr size_t WS_ENV    = 128;      // 225 (pad)
constexpr size_t WS_KW     = 384;      // 28800
constexpr size_t WS_PART   = 29184;    // partial[512][128] = 65536
constexpr size_t WS_XPROJ  = 94720;    // bf16[1024][128] (region reused)
constexpr size_t WS_XDW    = 225792;   // f32[1024][128] = 131072
constexpr size_t WS_OFFS   = 356864;   // 1843200
constexpr size_t WS_MASK   = 2200064;  // 921600
constexpr size_t WS_OUTPRE = 3121664;  // 131072

typedef short bf16x8 __attribute__((ext_vector_type(8)));
typedef float f32x4  __attribute__((ext_vector_type(4)));

__device__ __forceinline__ float sigmoidf_(float v) { return 1.f / (1.f + expf(-v)); }
__device__ __forceinline__ float siluf_(float v)    { return v / (1.f + expf(-v)); }

__device__ __forceinline__ unsigned short f2bf(float f) {
    unsigned u = __float_as_uint(f);
    unsigned r = u + 0x7FFFu + ((u >> 16) & 1u);   // round-to-nearest-even
    return (unsigned short)(r >> 16);
}
__device__ __forceinline__ float bf2f(unsigned short u) {
    return __uint_as_float((unsigned)u << 16);
}

// ---------------- K1: front (blocks 0-255) + kernel-MLP/env (blocks 256-312) ----------------
__device__ __forceinline__ void mlp_point(int k2i, int lane,
        const float* __restrict__ k1_w, const float* __restrict__ k1_b,
        const float* __restrict__ k2_w, const float* __restrict__ k2_b,
        const float* __restrict__ k3_w, const float* __restrict__ k3_b,
        float* __restrict__ ws) {
    int i = k2i / 15, j = k2i % 15;
    float ph = (-0.5f + (float)i * (1.f / 14.f)) * 2.f;
    float pw = (-0.5f + (float)j * (1.f / 14.f)) * 2.f;
    float h1[KHID], h2[KHID];
#pragma unroll
    for (int m = 0; m < KHID; m++)
        h1[m] = siluf_(fmaf(ph, k1_w[m], fmaf(pw, k1_w[KHID + m], k1_b[m])));
#pragma unroll
    for (int m = 0; m < KHID; m++) {
        float a = k2_b[m];
#pragma unroll
        for (int q = 0; q < KHID; q++) a = fmaf(h1[q], k2_w[q * KHID + m], a);
        h2[m] = siluf_(a);
    }
#pragma unroll
    for (int t = 0; t < 2; t++) {
        int col = lane + t * 64;
        float a = k3_b[col];
#pragma unroll
        for (int q = 0; q < KHID; q++) a = fmaf(h2[q], k3_w[q * C + col], a);
        ws[WS_KW + (size_t)k2i * C + col] = a;  // kw[g][k][c] = flat[g*7200 + k*32 + c]
    }
}

__global__ __launch_bounds__(256) void prep_front_kernel(const float* __restrict__ x,
        const float* __restrict__ raw_sigma,
        const float* __restrict__ w_in, const float* __restrict__ b_in,
        const float* __restrict__ dw_k, const float* __restrict__ dw_b,
        const float* __restrict__ pw_w, const float* __restrict__ pw_b,
        const float* __restrict__ k1_w, const float* __restrict__ k1_b,
        const float* __restrict__ k2_w, const float* __restrict__ k2_b,
        const float* __restrict__ k3_w, const float* __restrict__ k3_b,
        float* __restrict__ ws) {
    int tid = threadIdx.x;
    int b = blockIdx.x;
    if (b < 256) {
        __shared__ float xs[4][C], ts[4][C];
        unsigned short* xph = (unsigned short*)(ws + WS_XPROJ);
        int p0 = b * 4;
        int c = tid & 127, pp = tid >> 7;
#pragma unroll
        for (int q = 0; q < 2; q++) {
            int px = pp * 2 + q;
            int p = p0 + px;
            int h = p >> 5, w = p & 31;
            xs[px][c] = x[(size_t)p * C + c];
            float y = dw_b[c];
#pragma unroll
            for (int dy = 0; dy < 3; dy++) {
                int hh = h + dy - 1;
                if (hh < 0 || hh >= H) continue;
#pragma unroll
                for (int dx = 0; dx < 3; dx++) {
                    int wq = w + dx - 1;
                    if (wq < 0 || wq >= W) continue;
                    y = fmaf(x[((size_t)hh * W + wq) * C + c], dw_k[(dy * 3 + dx) * C + c], y);
                }
            }
            ts[px][c] = siluf_(y);
        }
        __syncthreads();
        float ap0 = b_in[c], ap1 = ap0, ad0 = pw_b[c], ad1 = ad0;
        int b0 = pp * 2, b1 = pp * 2 + 1;
        for (int i = 0; i < C; i += 4) {
#pragma unroll
            for (int u = 0; u < 4; u++) {
                float wi = w_in[(size_t)(i + u) * C + c];
                float pi = pw_w[(size_t)(i + u) * C + c];
                ap0 = fmaf(xs[b0][i + u], wi, ap0);
                ap1 = fmaf(xs[b1][i + u], wi, ap1);
                ad0 = fmaf(ts[b0][i + u], pi, ad0);
                ad1 = fmaf(ts[b1][i + u], pi, ad1);
            }
        }
        xph[(size_t)(p0 + b0) * C + c] = f2bf(ap0);
        xph[(size_t)(p0 + b1) * C + c] = f2bf(ap1);
        ws[WS_XDW + (size_t)(p0 + b0) * C + c] = ad0;   // f32: GEMM splits hi/lo itself
        ws[WS_XDW + (size_t)(p0 + b1) * C + c] = ad1;
    } else {
        int mb = b - 256;   // 0..56
        if (mb == 0) {
            __shared__ float red[256];
            float xsg = raw_sigma[0];
            float sp = fmaxf(xsg, 0.f) + log1pf(expf(-fabsf(xsg)));
            float sigma = fminf(fmaxf(sp, 0.001f), 0.5f);
            float inv2s2 = 1.f / (2.f * sigma * sigma);
            int i = tid / 15, j = tid % 15;
            float e = 0.f;
            if (tid < K2) {
                float gi = -0.5f + (float)i * (1.f / 14.f);
                float gj = -0.5f + (float)j * (1.f / 14.f);
                e = expf(-(gi * gi + gj * gj) * inv2s2);
            }
            red[tid] = e;
            __syncthreads();
            for (int s = 128; s > 0; s >>= 1) {
                if (tid < s) red[tid] += red[tid + s];
                __syncthreads();
            }
            float esum = fmaxf(red[0], 1e-8f);
            if (tid < K2) ws[WS_ENV + tid] = e / esum;
            if (tid < 64) mlp_point(224, tid, k1_w, k1_b, k2_w, k2_b, k3_w, k3_b, ws);
        } else {
            int k2i = (mb - 1) * 4 + (tid >> 6);  // 0..223
            mlp_point(k2i, tid & 63, k1_w, k1_b, k2_w, k2_b, k3_w, k3_b, ws);
        }
    }
}

// ---------------- K2: offs+mask GEMM via bf16x3 MFMA (Markidis split), 64x64 tile ----------------
__global__ __launch_bounds__(256) void offmsk_gemm_mfma(const float* __restrict__ xdw,
        const float* __restrict__ off_w, const float* __restrict__ off_b,
        const float* __restrict__ msk_w, const float* __restrict__ msk_b,
        const float* __restrict__ bos, const float* __restrict__ env,
        float* __restrict__ offs_out, float* __restrict__ mask_out) {
    __shared__ __align__(16) unsigned short As_hi[64][72];
    __shared__ __align__(16) unsigned short As_lo[64][72];
    __shared__ __align__(16) unsigned short Bs_hi[64][72];
    __shared__ __align__(16) unsigned short Bs_lo[64][72];
    int tid = threadIdx.x;
    int c0 = blockIdx.x * 64;
    int p0 = blockIdx.y * 64;

    int w = tid >> 6, l = tid & 63;
    int lr = l & 15, lk8 = (l >> 4) * 8;

    int n = tid & 63;
    int col = c0 + n;
    bool bvalid = col < NTOT;
    const float* wsrc = off_w + (bvalid && col < NOFF ? col : 0);
    int wstr = NOFF;
    if (bvalid && col >= NOFF) { wsrc = msk_w + (col - NOFF); wstr = NMSK; }

    f32x4 acc[4];
#pragma unroll
    for (int j = 0; j < 4; j++) acc[j] = (f32x4){0.f, 0.f, 0.f, 0.f};

    for (int kc = 0; kc < C; kc += 64) {
        if (kc) __syncthreads();
        {
            int r = tid >> 2, kq = (tid & 3) * 16;
#pragma unroll
            for (int i = 0; i < 4; i++) {
                float4 v = *(const float4*)&xdw[(size_t)(p0 + r) * C + kc + kq + i * 4];
                const float* vf = (const float*)&v;
#pragma unroll
                for (int u = 0; u < 4; u++) {
                    unsigned short hh = f2bf(vf[u]);
                    As_hi[r][kq + i * 4 + u] = hh;
                    As_lo[r][kq + i * 4 + u] = f2bf(vf[u] - bf2f(hh));
                }
            }
        }
        {
            int kg = tid >> 6;   // 0..3, 16 k each
#pragma unroll
            for (int i = 0; i < 16; i++) {
                int k = kg * 16 + i;
                float f = bvalid ? wsrc[(size_t)(kc + k) * wstr] : 0.f;
                unsigned short hh = f2bf(f);
                Bs_hi[n][k] = hh;
                Bs_lo[n][k] = f2bf(f - bf2f(hh));
            }
        }
        __syncthreads();

        bf16x8 a_hi[2], a_lo[2];
#pragma unroll
        for (int ks = 0; ks < 2; ks++) {
            a_hi[ks] = *(const bf16x8*)&As_hi[w * 16 + lr][ks * 32 + lk8];
            a_lo[ks] = *(const bf16x8*)&As_lo[w * 16 + lr][ks * 32 + lk8];
        }
#pragma unroll
        for (int j = 0; j < 4; j++) {
#pragma unroll
            for (int ks = 0; ks < 2; ks++) {
                bf16x8 b_hi = *(const bf16x8*)&Bs_hi[j * 16 + lr][ks * 32 + lk8];
                bf16x8 b_lo = *(const bf16x8*)&Bs_lo[j * 16 + lr][ks * 32 + lk8];
                acc[j] = __builtin_amdgcn_mfma_f32_16x16x32_bf16(a_hi[ks], b_hi, acc[j], 0, 0, 0);
                acc[j] = __builtin_amdgcn_mfma_f32_16x16x32_bf16(a_lo[ks], b_hi, acc[j], 0, 0, 0);
                acc[j] = __builtin_amdgcn_mfma_f32_16x16x32_bf16(a_hi[ks], b_lo, acc[j], 0, 0, 0);
            }
        }
    }

#pragma unroll
    for (int j = 0; j < 4; j++) {
        int ocol = c0 + j * 16 + lr;
        if (ocol < NTOT) {
            float bias, sc;
            float* obase;
            int ostr;
            if (ocol < NOFF) {
                bias = off_b[ocol]; sc = bos[0];
                obase = offs_out + ocol; ostr = NOFF;
            } else {
                int m0 = ocol - NOFF;
                bias = msk_b[m0]; sc = env[m0 % K2];
                obase = mask_out + m0; ostr = NMSK;
            }
            int row0 = p0 + w * 16 + (l >> 4) * 4;
#pragma unroll
            for (int r = 0; r < 4; r++)
                obase[(size_t)(row0 + r) * ostr] = (acc[j][r] + bias) * sc;
        }
    }
}

// ---------------- K3: g-split sampler, softmax version, 2-stage pipelined gather loop ----------------
// launch_bounds(256,6): VGPR cap ~80 (6 blk/CU, 24 waves) -> room to keep next iter's
// gathers in flight while current iter's FMA tree runs.
__global__ __launch_bounds__(256, 6) void sampler_kernel(const float* __restrict__ ws_offs,
        const float* __restrict__ ws_mask, const unsigned short* __restrict__ xprojh,
        const float* __restrict__ kwf, float* __restrict__ outpre,
        float* __restrict__ partial) {
    int blk = blockIdx.x;
    int pp = blk >> 2;           // pixel pair 0..511
    int g  = blk & 3;
    int p0 = pp * 2;
    int h = p0 >> 5;             // both pixels same row
    int tid = threadIdx.x;

    __shared__ float   attn_s[2][K2];
    __shared__ float4  wgt_s[2][K2];
    __shared__ ushort4 loc_s[2][K2];
    __shared__ float4  rbuf[16][16];

    // ---- softmax for (px) on waves 0,1 ----
    if (tid < 128) {
        int px = tid >> 6, lane = tid & 63;
        const float* mrow = ws_mask + (size_t)(p0 + px) * NMSK + g * K2;
        float v[4];
        float mx = -1e30f;
#pragma unroll
        for (int q = 0; q < 4; q++) {
            int k = lane + q * 64;
            v[q] = (k < K2) ? mrow[k] : -1e30f;
            mx = fmaxf(mx, v[q]);
        }
#pragma unroll
        for (int s = 32; s > 0; s >>= 1) mx = fmaxf(mx, __shfl_xor(mx, s));
        float sum = 0.f;
#pragma unroll
        for (int q = 0; q < 4; q++) {
            int k = lane + q * 64;
            v[q] = (k < K2) ? expf(v[q] - mx) : 0.f;
            sum += v[q];
        }
#pragma unroll
        for (int s = 32; s > 0; s >>= 1) sum += __shfl_xor(sum, s);
        float inv = 1.f / sum;
#pragma unroll
        for (int q = 0; q < 4; q++) {
            int k = lane + q * 64;
            if (k < K2) attn_s[px][k] = v[q] * inv;
        }
    }
    __syncthreads();

    // ---- bilinear weights (attn*valid folded) + packed corner pixel indices ----
    for (int e = tid; e < 2 * K2; e += 256) {
        int px = (e >= K2) ? 1 : 0;
        int k = e - px * K2;
        int p = p0 + px;
        int w = p & 31;
        float2 o = *(const float2*)&ws_offs[(size_t)p * NOFF + (g * K2 + k) * 2];
        float abs_h = (float)(h + k / 15 - 7) + o.x;
        float abs_w = (float)(w + k % 15 - 7) + o.y;
        float validf = (abs_h < 0.f || abs_h > 31.f || abs_w < 0.f || abs_w > 31.f) ? 0.f : 1.f;
        float ah = fminf(fmaxf(abs_h, 0.f), 31.f);
        float aw = fminf(fmaxf(abs_w, 0.f), 31.f);
        int hf = (int)ah, wf = (int)aw;
        int hc = min(hf + 1, 31), wc = min(wf + 1, 31);
        float hwt = ah - (float)hf, wwt = aw - (float)wf;
        float a = attn_s[px][k] * validf;
        float u0 = 1.f - hwt, u1 = 1.f - wwt;
        wgt_s[px][k] = make_float4(a * u0 * u1, a * u0 * wwt, a * hwt * u1, a * hwt * wwt);
        loc_s[px][k] = make_ushort4((unsigned short)(hf * W + wf), (unsigned short)(hf * W + wc),
                                    (unsigned short)(hc * W + wf), (unsigned short)(hc * W + wc));
    }
    __syncthreads();

    // ---- gathers: cq(8) x px(2) x s(16); 2-stage software pipeline ----
    {
        int cq = tid & 7;
        int px = (tid >> 3) & 1;
        int s  = tid >> 4;
        int k0 = s * 15;
        int k1 = min(k0 + 15, K2);
        const unsigned short* xpg = xprojh + g * GC + cq * 4;
        const float* kwg = kwf + (size_t)g * (K2 * GC) + cq * 4;
        float4 acc = make_float4(0.f, 0.f, 0.f, 0.f);

        // prologue: issue loads for k0
        float4  Wv = wgt_s[px][k0];
        ushort4 L  = loc_s[px][k0];
        ushort4 u00 = *(const ushort4*)(xpg + (size_t)L.x * C);
        ushort4 u01 = *(const ushort4*)(xpg + (size_t)L.y * C);
        ushort4 u10 = *(const ushort4*)(xpg + (size_t)L.z * C);
        ushort4 u11 = *(const ushort4*)(xpg + (size_t)L.w * C);
        float4  kw4 = *(const float4*)(kwg + k0 * GC);

        for (int k = k0; k < k1; k++) {
            // stage next iteration's loads before consuming current
            float4  Wv_n;
            ushort4 u00n, u01n, u10n, u11n;
            float4  kw4n;
            if (k + 1 < k1) {
                Wv_n = wgt_s[px][k + 1];
                ushort4 Ln = loc_s[px][k + 1];
                u00n = *(const ushort4*)(xpg + (size_t)Ln.x * C);
                u01n = *(const ushort4*)(xpg + (size_t)Ln.y * C);
                u10n = *(const ushort4*)(xpg + (size_t)Ln.z * C);
                u11n = *(const ushort4*)(xpg + (size_t)Ln.w * C);
                kw4n = *(const float4*)(kwg + (k + 1) * GC);
            }
            float sx = fmaf(Wv.w, bf2f(u11.x), fmaf(Wv.z, bf2f(u10.x),
                       fmaf(Wv.y, bf2f(u01.x), Wv.x * bf2f(u00.x))));
            float sy = fmaf(Wv.w, bf2f(u11.y), fmaf(Wv.z, bf2f(u10.y),
                       fmaf(Wv.y, bf2f(u01.y), Wv.x * bf2f(u00.y))));
            float sz = fmaf(Wv.w, bf2f(u11.z), fmaf(Wv.z, bf2f(u10.z),
                       fmaf(Wv.y, bf2f(u01.z), Wv.x * bf2f(u00.z))));
            float sw = fmaf(Wv.w, bf2f(u11.w), fmaf(Wv.z, bf2f(u10.w),
                       fmaf(Wv.y, bf2f(u01.w), Wv.x * bf2f(u00.w))));
            acc.x = fmaf(kw4.x, sx, acc.x);
            acc.y = fmaf(kw4.y, sy, acc.y);
            acc.z = fmaf(kw4.z, sz, acc.z);
            acc.w = fmaf(kw4.w, sw, acc.w);
            if (k + 1 < k1) {
                Wv = Wv_n; kw4 = kw4n;
                u00 = u00n; u01 = u01n; u10 = u10n; u11 = u11n;
            }
        }
        rbuf[s][px * 8 + cq] = acc;
    }
    __syncthreads();

    // ---- reduce over s(16); outpre slice; partial via shfl over px ----
    if (tid < 64) {
        int px = tid >> 5, cc = tid & 31;
        int cq = cc >> 2, j = cc & 3;
        float v = 0.f;
#pragma unroll
        for (int s = 0; s < 16; s++)
            v += ((const float*)&rbuf[s][px * 8 + cq])[j];
        outpre[(size_t)(p0 + px) * C + g * GC + cc] = v;
        float pv = v + __shfl_xor(v, 32);   // sum over px within wave 0
        if (px == 0)
            partial[(size_t)pp * C + g * GC + cc] = pv;
    }
}

// ---------------- K4: redundant pooled reduce + SE MLP + final GEMV (4 px/block) ----------------
__global__ __launch_bounds__(256) void finale_kernel(const float* __restrict__ outpre,
        const float* __restrict__ partial,
        const float* __restrict__ se1_w, const float* __restrict__ se1_b,
        const float* __restrict__ se2_w, const float* __restrict__ se2_b,
        const float* __restrict__ w_out, const float* __restrict__ b_out,
        float* __restrict__ out) {
    int tid = threadIdx.x;
    __shared__ float tmp[8][132];
    __shared__ float pooled[C];
    __shared__ float hid[KHID];
    __shared__ float scl[C];
    __shared__ float v[4][C];

    {
        int bg = tid >> 5, c4 = (tid & 31) * 4;
        float4 s4 = make_float4(0.f, 0.f, 0.f, 0.f);
        for (int i = 0; i < 64; i++) {
            float4 pv = *(const float4*)&partial[(size_t)(bg * 64 + i) * C + c4];
            s4.x += pv.x; s4.y += pv.y; s4.z += pv.z; s4.w += pv.w;
        }
        *(float4*)&tmp[bg][c4] = s4;
    }
    __syncthreads();
    if (tid < C) {
        float s = 0.f;
#pragma unroll
        for (int g = 0; g < 8; g++) s += tmp[g][tid];
        pooled[tid] = s * (1.f / 1024.f);
    }
    __syncthreads();
    if (tid < KHID) {
        float a = se1_b[tid];
        for (int cc = 0; cc < C; cc++) a = fmaf(pooled[cc], se1_w[cc * KHID + tid], a);
        hid[tid] = siluf_(a);
    }
    __syncthreads();
    if (tid < C) {
        float a = se2_b[tid];
#pragma unroll
        for (int q = 0; q < KHID; q++) a = fmaf(hid[q], se2_w[q * C + tid], a);
        scl[tid] = sigmoidf_(a);
    }
    __syncthreads();

    int p0 = blockIdx.x * 4;
    int c = tid & 127, pp = tid >> 7;
#pragma unroll
    for (int q = 0; q < 2; q++) {
        int px = pp * 2 + q;
        v[px][c] = outpre[(size_t)(p0 + px) * C + c] * scl[c];
    }
    __syncthreads();
    float a0 = b_out[c], a1 = b_out[c];
    int b0 = pp * 2, b1 = pp * 2 + 1;
    for (int i = 0; i < C; i += 4) {
#pragma unroll
        for (int u = 0; u < 4; u++) {
            float wv = w_out[(size_t)(i + u) * C + c];
            a0 = fmaf(v[b0][i + u], wv, a0);
            a1 = fmaf(v[b1][i + u], wv, a1);
        }
    }
    out[(size_t)(p0 + b0) * C + c] = a0;
    out[(size_t)(p0 + b1) * C + c] = a1;
}

extern "C" void kernel_launch(void* const* d_in, const int* in_sizes, int n_in,
                              void* d_out, int out_size, void* d_ws, size_t ws_size,
                              hipStream_t stream) {
    const float* x         = (const float*)d_in[0];
    const float* raw_sigma = (const float*)d_in[1];
    const float* bos       = (const float*)d_in[2];
    const float* w_in      = (const float*)d_in[3];
    const float* b_in      = (const float*)d_in[4];
    const float* w_out     = (const float*)d_in[5];
    const float* b_out     = (const float*)d_in[6];
    const float* dw_k      = (const float*)d_in[7];
    const float* dw_b      = (const float*)d_in[8];
    const float* pw_w      = (const float*)d_in[9];
    const float* pw_b      = (const float*)d_in[10];
    const float* off_w     = (const float*)d_in[11];
    const float* off_b     = (const float*)d_in[12];
    const float* msk_w     = (const float*)d_in[13];
    const float* msk_b     = (const float*)d_in[14];
    const float* k1_w      = (const float*)d_in[15];
    const float* k1_b      = (const float*)d_in[16];
    const float* k2_w      = (const float*)d_in[17];
    const float* k2_b      = (const float*)d_in[18];
    const float* k3_w      = (const float*)d_in[19];
    const float* k3_b      = (const float*)d_in[20];
    const float* se1_w     = (const float*)d_in[21];
    const float* se1_b     = (const float*)d_in[22];
    const float* se2_w     = (const float*)d_in[23];
    const float* se2_b     = (const float*)d_in[24];

    float* ws  = (float*)d_ws;
    float* out = (float*)d_out;

    prep_front_kernel<<<313, 256, 0, stream>>>(x, raw_sigma, w_in, b_in, dw_k, dw_b,
                                               pw_w, pw_b, k1_w, k1_b, k2_w, k2_b,
                                               k3_w, k3_b, ws);

    dim3 gg((NTOT + 63) / 64, NPIX / 64);   // 43 x 16 = 688 blocks
    offmsk_gemm_mfma<<<gg, 256, 0, stream>>>(ws + WS_XDW, off_w, off_b, msk_w, msk_b,
                                             bos, ws + WS_ENV, ws + WS_OFFS, ws + WS_MASK);

    sampler_kernel<<<NPIX * 2, 256, 0, stream>>>(ws + WS_OFFS, ws + WS_MASK,
                                                 (const unsigned short*)(ws + WS_XPROJ),
                                                 ws + WS_KW, ws + WS_OUTPRE, ws + WS_PART);

    finale_kernel<<<NPIX / 4, 256, 0, stream>>>(ws + WS_OUTPRE, ws + WS_PART,
                                                se1_w, se1_b, se2_w, se2_b,
                                                w_out, b_out, out);
}

// Round 14
// 66.919 us; speedup vs baseline: 1.0475x; 1.0475x over previous
//
#include <hip/hip_runtime.h>
#include <math.h>

constexpr int H = 32, W = 32, C = 128, G = 4, K = 15, K2 = 225, GC = 32;
constexpr int NPIX = H * W;
constexpr int NOFF = G * K2 * 2;   // 1800
constexpr int NMSK = G * K2;       // 900
constexpr int NTOT = NOFF + NMSK;  // 2700
constexpr int KHID = 32;

// workspace layout (float offsets)
constexpr size_t WS_ENV    = 128;      // 225 (pad)
constexpr size_t WS_KW     = 384;      // 28800
constexpr size_t WS_PART   = 29184;    // partial[512][128] = 65536
constexpr size_t WS_XPROJ  = 94720;    // bf16[1024][128] (region reused)
constexpr size_t WS_XDW    = 225792;   // f32[1024][128] = 131072
constexpr size_t WS_OFFS   = 356864;   // 1843200
constexpr size_t WS_MASK   = 2200064;  // 921600
constexpr size_t WS_OUTPRE = 3121664;  // 131072

__device__ __forceinline__ float sigmoidf_(float v) { return 1.f / (1.f + expf(-v)); }
__device__ __forceinline__ float siluf_(float v)    { return v / (1.f + expf(-v)); }

__device__ __forceinline__ unsigned short f2bf(float f) {
    unsigned u = __float_as_uint(f);
    unsigned r = u + 0x7FFFu + ((u >> 16) & 1u);   // round-to-nearest-even
    return (unsigned short)(r >> 16);
}
__device__ __forceinline__ float bf2f(unsigned short u) {
    return __uint_as_float((unsigned)u << 16);
}

// ---------------- K1: front (blocks 0-255) + kernel-MLP/env (blocks 256-312) ----------------
__device__ __forceinline__ void mlp_point(int k2i, int lane,
        const float* __restrict__ k1_w, const float* __restrict__ k1_b,
        const float* __restrict__ k2_w, const float* __restrict__ k2_b,
        const float* __restrict__ k3_w, const float* __restrict__ k3_b,
        float* __restrict__ ws) {
    int i = k2i / 15, j = k2i % 15;
    float ph = (-0.5f + (float)i * (1.f / 14.f)) * 2.f;
    float pw = (-0.5f + (float)j * (1.f / 14.f)) * 2.f;
    float h1[KHID], h2[KHID];
#pragma unroll
    for (int m = 0; m < KHID; m++)
        h1[m] = siluf_(fmaf(ph, k1_w[m], fmaf(pw, k1_w[KHID + m], k1_b[m])));
#pragma unroll
    for (int m = 0; m < KHID; m++) {
        float a = k2_b[m];
#pragma unroll
        for (int q = 0; q < KHID; q++) a = fmaf(h1[q], k2_w[q * KHID + m], a);
        h2[m] = siluf_(a);
    }
#pragma unroll
    for (int t = 0; t < 2; t++) {
        int col = lane + t * 64;
        float a = k3_b[col];
#pragma unroll
        for (int q = 0; q < KHID; q++) a = fmaf(h2[q], k3_w[q * C + col], a);
        ws[WS_KW + (size_t)k2i * C + col] = a;  // kw[g][k][c] = flat[g*7200 + k*32 + c]
    }
}

__global__ __launch_bounds__(256) void prep_front_kernel(const float* __restrict__ x,
        const float* __restrict__ raw_sigma,
        const float* __restrict__ w_in, const float* __restrict__ b_in,
        const float* __restrict__ dw_k, const float* __restrict__ dw_b,
        const float* __restrict__ pw_w, const float* __restrict__ pw_b,
        const float* __restrict__ k1_w, const float* __restrict__ k1_b,
        const float* __restrict__ k2_w, const float* __restrict__ k2_b,
        const float* __restrict__ k3_w, const float* __restrict__ k3_b,
        float* __restrict__ ws) {
    int tid = threadIdx.x;
    int b = blockIdx.x;
    if (b < 256) {
        __shared__ float xs[4][C], ts[4][C];
        unsigned short* xph = (unsigned short*)(ws + WS_XPROJ);
        int p0 = b * 4;
        int c = tid & 127, pp = tid >> 7;
#pragma unroll
        for (int q = 0; q < 2; q++) {
            int px = pp * 2 + q;
            int p = p0 + px;
            int h = p >> 5, w = p & 31;
            xs[px][c] = x[(size_t)p * C + c];
            float y = dw_b[c];
#pragma unroll
            for (int dy = 0; dy < 3; dy++) {
                int hh = h + dy - 1;
                if (hh < 0 || hh >= H) continue;
#pragma unroll
                for (int dx = 0; dx < 3; dx++) {
                    int wq = w + dx - 1;
                    if (wq < 0 || wq >= W) continue;
                    y = fmaf(x[((size_t)hh * W + wq) * C + c], dw_k[(dy * 3 + dx) * C + c], y);
                }
            }
            ts[px][c] = siluf_(y);
        }
        __syncthreads();
        float ap0 = b_in[c], ap1 = ap0, ad0 = pw_b[c], ad1 = ad0;
        int b0 = pp * 2, b1 = pp * 2 + 1;
        for (int i = 0; i < C; i += 4) {
#pragma unroll
            for (int u = 0; u < 4; u++) {
                float wi = w_in[(size_t)(i + u) * C + c];
                float pi = pw_w[(size_t)(i + u) * C + c];
                ap0 = fmaf(xs[b0][i + u], wi, ap0);
                ap1 = fmaf(xs[b1][i + u], wi, ap1);
                ad0 = fmaf(ts[b0][i + u], pi, ad0);
                ad1 = fmaf(ts[b1][i + u], pi, ad1);
            }
        }
        xph[(size_t)(p0 + b0) * C + c] = f2bf(ap0);
        xph[(size_t)(p0 + b1) * C + c] = f2bf(ap1);
        ws[WS_XDW + (size_t)(p0 + b0) * C + c] = ad0;
        ws[WS_XDW + (size_t)(p0 + b1) * C + c] = ad1;
    } else {
        int mb = b - 256;   // 0..56
        if (mb == 0) {
            __shared__ float red[256];
            float xsg = raw_sigma[0];
            float sp = fmaxf(xsg, 0.f) + log1pf(expf(-fabsf(xsg)));
            float sigma = fminf(fmaxf(sp, 0.001f), 0.5f);
            float inv2s2 = 1.f / (2.f * sigma * sigma);
            int i = tid / 15, j = tid % 15;
            float e = 0.f;
            if (tid < K2) {
                float gi = -0.5f + (float)i * (1.f / 14.f);
                float gj = -0.5f + (float)j * (1.f / 14.f);
                e = expf(-(gi * gi + gj * gj) * inv2s2);
            }
            red[tid] = e;
            __syncthreads();
            for (int s = 128; s > 0; s >>= 1) {
                if (tid < s) red[tid] += red[tid + s];
                __syncthreads();
            }
            float esum = fmaxf(red[0], 1e-8f);
            if (tid < K2) ws[WS_ENV + tid] = e / esum;
            if (tid < 64) mlp_point(224, tid, k1_w, k1_b, k2_w, k2_b, k3_w, k3_b, ws);
        } else {
            int k2i = (mb - 1) * 4 + (tid >> 6);  // 0..223
            mlp_point(k2i, tid & 63, k1_w, k1_b, k2_w, k2_b, k3_w, k3_b, ws);
        }
    }
}

// ---------------- K2: offs+mask GEMM, 64x64 tile, 4x4 per thread (688 blocks) ----------------
__global__ __launch_bounds__(256) void offmsk_gemm(const float* __restrict__ A,
        const float* __restrict__ off_w, const float* __restrict__ off_b,
        const float* __restrict__ msk_w, const float* __restrict__ msk_b,
        const float* __restrict__ bos, const float* __restrict__ env,
        float* __restrict__ offs_out, float* __restrict__ mask_out) {
    __shared__ float At[32][72];
    __shared__ float Bs[32][64];
    int tid = threadIdx.x;
    int c0 = blockIdx.x * 64;
    int p0 = blockIdx.y * 64;
    int tx = tid & 15, ty = tid >> 4;
    float acc[4][4];
#pragma unroll
    for (int i = 0; i < 4; i++)
#pragma unroll
        for (int j = 0; j < 4; j++) acc[i][j] = 0.f;
    int cL = (tid * 4) & 63;
    int kL = (tid * 4) >> 6;
    int cB = c0 + cL;
    const float* bptr = nullptr; int bstride = 0;
    if (cB < NOFF)       { bptr = off_w + cB;          bstride = NOFF; }
    else if (cB < NTOT)  { bptr = msk_w + (cB - NOFF); bstride = NMSK; }
    int rA = tid >> 3, k4A = (tid & 7) * 4;
    for (int kt = 0; kt < C; kt += 32) {
        if (kt) __syncthreads();
#pragma unroll
        for (int pass = 0; pass < 2; pass++) {
            int r = rA + pass * 32;
            float4 v = *(const float4*)&A[(size_t)(p0 + r) * C + kt + k4A];
            At[k4A + 0][r] = v.x; At[k4A + 1][r] = v.y;
            At[k4A + 2][r] = v.z; At[k4A + 3][r] = v.w;
            int k = kL + pass * 16;
            float4 bv = make_float4(0.f, 0.f, 0.f, 0.f);
            if (bptr) bv = *(const float4*)&bptr[(size_t)(kt + k) * bstride];
            *(float4*)&Bs[k][cL] = bv;
        }
        __syncthreads();
#pragma unroll
        for (int k = 0; k < 32; k++) {
            float4 a4 = *(const float4*)&At[k][ty * 4];
            float4 b4 = *(const float4*)&Bs[k][tx * 4];
            const float av[4] = {a4.x, a4.y, a4.z, a4.w};
            const float bv[4] = {b4.x, b4.y, b4.z, b4.w};
#pragma unroll
            for (int i = 0; i < 4; i++)
#pragma unroll
                for (int j = 0; j < 4; j++)
                    acc[i][j] = fmaf(av[i], bv[j], acc[i][j]);
        }
    }
    int colbase = c0 + tx * 4;
    if (colbase >= NTOT) return;
    float bias[4], sc[4];
    float* obase; int ostride;
    if (colbase < NOFF) {
        float s = bos[0];
#pragma unroll
        for (int j = 0; j < 4; j++) { bias[j] = off_b[colbase + j]; sc[j] = s; }
        obase = offs_out + colbase; ostride = NOFF;
    } else {
        int m0 = colbase - NOFF;
#pragma unroll
        for (int j = 0; j < 4; j++) { bias[j] = msk_b[m0 + j]; sc[j] = env[(m0 + j) % K2]; }
        obase = mask_out + m0; ostride = NMSK;
    }
#pragma unroll
    for (int i = 0; i < 4; i++) {
        size_t row = (size_t)(p0 + ty * 4 + i);
        float4 r0 = make_float4((acc[i][0] + bias[0]) * sc[0], (acc[i][1] + bias[1]) * sc[1],
                                (acc[i][2] + bias[2]) * sc[2], (acc[i][3] + bias[3]) * sc[3]);
        *(float4*)&obase[row * ostride] = r0;
    }
}

// ---------------- K3: g-split sampler (2048 blocks), bf16 gathers + invalid-tap skip ----------------
__global__ __launch_bounds__(256, 8) void sampler_kernel(const float* __restrict__ ws_offs,
        const float* __restrict__ ws_mask, const unsigned short* __restrict__ xprojh,
        const float* __restrict__ kwf, float* __restrict__ outpre,
        float* __restrict__ partial) {
    int blk = blockIdx.x;
    int pp = blk >> 2;           // pixel pair 0..511
    int g  = blk & 3;
    int p0 = pp * 2;
    int h = p0 >> 5;             // both pixels same row
    int tid = threadIdx.x;

    __shared__ float   attn_s[2][K2];      // 1.8 KB
    __shared__ float4  wgt_s[2][K2];       // 7.2 KB
    __shared__ ushort4 loc_s[2][K2];       // 3.6 KB
    __shared__ float4  rbuf[16][16];       // 4.0 KB

    // ---- softmax for (px) on waves 0,1 ----
    if (tid < 128) {
        int px = tid >> 6, lane = tid & 63;
        const float* mrow = ws_mask + (size_t)(p0 + px) * NMSK + g * K2;
        float v[4];
        float mx = -1e30f;
#pragma unroll
        for (int q = 0; q < 4; q++) {
            int k = lane + q * 64;
            v[q] = (k < K2) ? mrow[k] : -1e30f;
            mx = fmaxf(mx, v[q]);
        }
#pragma unroll
        for (int s = 32; s > 0; s >>= 1) mx = fmaxf(mx, __shfl_xor(mx, s));
        float sum = 0.f;
#pragma unroll
        for (int q = 0; q < 4; q++) {
            int k = lane + q * 64;
            v[q] = (k < K2) ? expf(v[q] - mx) : 0.f;
            sum += v[q];
        }
#pragma unroll
        for (int s = 32; s > 0; s >>= 1) sum += __shfl_xor(sum, s);
        float inv = 1.f / sum;
#pragma unroll
        for (int q = 0; q < 4; q++) {
            int k = lane + q * 64;
            if (k < K2) attn_s[px][k] = v[q] * inv;
        }
    }
    __syncthreads();

    // ---- bilinear weights (attn*valid folded) + packed corner pixel indices ----
    for (int e = tid; e < 2 * K2; e += 256) {
        int px = (e >= K2) ? 1 : 0;
        int k = e - px * K2;
        int p = p0 + px;
        int w = p & 31;
        float2 o = *(const float2*)&ws_offs[(size_t)p * NOFF + (g * K2 + k) * 2];
        float abs_h = (float)(h + k / 15 - 7) + o.x;
        float abs_w = (float)(w + k % 15 - 7) + o.y;
        float validf = (abs_h < 0.f || abs_h > 31.f || abs_w < 0.f || abs_w > 31.f) ? 0.f : 1.f;
        float ah = fminf(fmaxf(abs_h, 0.f), 31.f);
        float aw = fminf(fmaxf(abs_w, 0.f), 31.f);
        int hf = (int)ah, wf = (int)aw;
        int hc = min(hf + 1, 31), wc = min(wf + 1, 31);
        float hwt = ah - (float)hf, wwt = aw - (float)wf;
        float a = attn_s[px][k] * validf;
        float u0 = 1.f - hwt, u1 = 1.f - wwt;
        wgt_s[px][k] = make_float4(a * u0 * u1, a * u0 * wwt, a * hwt * u1, a * hwt * wwt);
        loc_s[px][k] = make_ushort4((unsigned short)(hf * W + wf), (unsigned short)(hf * W + wc),
                                    (unsigned short)(hc * W + wf), (unsigned short)(hc * W + wc));
    }
    __syncthreads();

    // ---- gathers: cq(8) x px(2) x s(16), 15 k's per thread; bf16 xproj, skip a==0 ----
    {
        int cq = tid & 7;
        int px = (tid >> 3) & 1;
        int s  = tid >> 4;
        int k0 = s * 15;
        int k1 = min(k0 + 15, K2);
        const unsigned short* xpg = xprojh + g * GC + cq * 4;
        const float* kwg = kwf + (size_t)g * (K2 * GC) + cq * 4;
        float4 acc = make_float4(0.f, 0.f, 0.f, 0.f);
        for (int k = k0; k < k1; k++) {
            float4 Wv = wgt_s[px][k];
            // weights are all >= 0 and sum to attn*valid: sum==0 <=> zero contribution
            if (Wv.x + Wv.y + Wv.z + Wv.w == 0.f) continue;
            ushort4 L = loc_s[px][k];
            ushort4 u00 = *(const ushort4*)(xpg + (size_t)L.x * C);
            ushort4 u01 = *(const ushort4*)(xpg + (size_t)L.y * C);
            ushort4 u10 = *(const ushort4*)(xpg + (size_t)L.z * C);
            ushort4 u11 = *(const ushort4*)(xpg + (size_t)L.w * C);
            float4 kw4 = *(const float4*)(kwg + k * GC);
            float sx = fmaf(Wv.w, bf2f(u11.x), fmaf(Wv.z, bf2f(u10.x),
                       fmaf(Wv.y, bf2f(u01.x), Wv.x * bf2f(u00.x))));
            float sy = fmaf(Wv.w, bf2f(u11.y), fmaf(Wv.z, bf2f(u10.y),
                       fmaf(Wv.y, bf2f(u01.y), Wv.x * bf2f(u00.y))));
            float sz = fmaf(Wv.w, bf2f(u11.z), fmaf(Wv.z, bf2f(u10.z),
                       fmaf(Wv.y, bf2f(u01.z), Wv.x * bf2f(u00.z))));
            float sw = fmaf(Wv.w, bf2f(u11.w), fmaf(Wv.z, bf2f(u10.w),
                       fmaf(Wv.y, bf2f(u01.w), Wv.x * bf2f(u00.w))));
            acc.x = fmaf(kw4.x, sx, acc.x);
            acc.y = fmaf(kw4.y, sy, acc.y);
            acc.z = fmaf(kw4.z, sz, acc.z);
            acc.w = fmaf(kw4.w, sw, acc.w);
        }
        rbuf[s][px * 8 + cq] = acc;
    }
    __syncthreads();

    // ---- reduce over s(16); outpre slice; partial via shfl over px ----
    if (tid < 64) {
        int px = tid >> 5, cc = tid & 31;
        int cq = cc >> 2, j = cc & 3;
        float v = 0.f;
#pragma unroll
        for (int s = 0; s < 16; s++)
            v += ((const float*)&rbuf[s][px * 8 + cq])[j];
        outpre[(size_t)(p0 + px) * C + g * GC + cc] = v;
        float pv = v + __shfl_xor(v, 32);   // sum over px within wave 0
        if (px == 0)
            partial[(size_t)pp * C + g * GC + cc] = pv;
    }
}

// ---------------- K4: redundant pooled reduce + SE MLP + final GEMV (4 px/block) ----------------
__global__ __launch_bounds__(256) void finale_kernel(const float* __restrict__ outpre,
        const float* __restrict__ partial,
        const float* __restrict__ se1_w, const float* __restrict__ se1_b,
        const float* __restrict__ se2_w, const float* __restrict__ se2_b,
        const float* __restrict__ w_out, const float* __restrict__ b_out,
        float* __restrict__ out) {
    int tid = threadIdx.x;
    __shared__ float tmp[8][132];
    __shared__ float pooled[C];
    __shared__ float hid[KHID];
    __shared__ float scl[C];
    __shared__ float v[4][C];

    // pooled reduce over 512 partial rows: 8 block-groups x 64 rows
    {
        int bg = tid >> 5, c4 = (tid & 31) * 4;
        float4 s4 = make_float4(0.f, 0.f, 0.f, 0.f);
        for (int i = 0; i < 64; i++) {
            float4 pv = *(const float4*)&partial[(size_t)(bg * 64 + i) * C + c4];
            s4.x += pv.x; s4.y += pv.y; s4.z += pv.z; s4.w += pv.w;
        }
        *(float4*)&tmp[bg][c4] = s4;
    }
    __syncthreads();
    if (tid < C) {
        float s = 0.f;
#pragma unroll
        for (int g = 0; g < 8; g++) s += tmp[g][tid];
        pooled[tid] = s * (1.f / 1024.f);
    }
    __syncthreads();
    if (tid < KHID) {
        float a = se1_b[tid];
        for (int cc = 0; cc < C; cc++) a = fmaf(pooled[cc], se1_w[cc * KHID + tid], a);
        hid[tid] = siluf_(a);
    }
    __syncthreads();
    if (tid < C) {
        float a = se2_b[tid];
#pragma unroll
        for (int q = 0; q < KHID; q++) a = fmaf(hid[q], se2_w[q * C + tid], a);
        scl[tid] = sigmoidf_(a);
    }
    __syncthreads();

    int p0 = blockIdx.x * 4;
    int c = tid & 127, pp = tid >> 7;
#pragma unroll
    for (int q = 0; q < 2; q++) {
        int px = pp * 2 + q;
        v[px][c] = outpre[(size_t)(p0 + px) * C + c] * scl[c];
    }
    __syncthreads();
    float a0 = b_out[c], a1 = b_out[c];
    int b0 = pp * 2, b1 = pp * 2 + 1;
    for (int i = 0; i < C; i += 4) {
#pragma unroll
        for (int u = 0; u < 4; u++) {
            float wv = w_out[(size_t)(i + u) * C + c];
            a0 = fmaf(v[b0][i + u], wv, a0);
            a1 = fmaf(v[b1][i + u], wv, a1);
        }
    }
    out[(size_t)(p0 + b0) * C + c] = a0;
    out[(size_t)(p0 + b1) * C + c] = a1;
}

extern "C" void kernel_launch(void* const* d_in, const int* in_sizes, int n_in,
                              void* d_out, int out_size, void* d_ws, size_t ws_size,
                              hipStream_t stream) {
    const float* x         = (const float*)d_in[0];
    const float* raw_sigma = (const float*)d_in[1];
    const float* bos       = (const float*)d_in[2];
    const float* w_in      = (const float*)d_in[3];
    const float* b_in      = (const float*)d_in[4];
    const float* w_out     = (const float*)d_in[5];
    const float* b_out     = (const float*)d_in[6];
    const float* dw_k      = (const float*)d_in[7];
    const float* dw_b      = (const float*)d_in[8];
    const float* pw_w      = (const float*)d_in[9];
    const float* pw_b      = (const float*)d_in[10];
    const float* off_w     = (const float*)d_in[11];
    const float* off_b     = (const float*)d_in[12];
    const float* msk_w     = (const float*)d_in[13];
    const float* msk_b     = (const float*)d_in[14];
    const float* k1_w      = (const float*)d_in[15];
    const float* k1_b      = (const float*)d_in[16];
    const float* k2_w      = (const float*)d_in[17];
    const float* k2_b      = (const float*)d_in[18];
    const float* k3_w      = (const float*)d_in[19];
    const float* k3_b      = (const float*)d_in[20];
    const float* se1_w     = (const float*)d_in[21];
    const float* se1_b     = (const float*)d_in[22];
    const float* se2_w     = (const float*)d_in[23];
    const float* se2_b     = (const float*)d_in[24];

    float* ws  = (float*)d_ws;
    float* out = (float*)d_out;

    prep_front_kernel<<<313, 256, 0, stream>>>(x, raw_sigma, w_in, b_in, dw_k, dw_b,
                                               pw_w, pw_b, k1_w, k1_b, k2_w, k2_b,
                                               k3_w, k3_b, ws);

    dim3 gg((NTOT + 63) / 64, NPIX / 64);   // 43 x 16 = 688 blocks
    offmsk_gemm<<<gg, 256, 0, stream>>>(ws + WS_XDW, off_w, off_b, msk_w, msk_b, bos,
                                        ws + WS_ENV, ws + WS_OFFS, ws + WS_MASK);

    sampler_kernel<<<NPIX * 2, 256, 0, stream>>>(ws + WS_OFFS, ws + WS_MASK,
                                                 (const unsigned short*)(ws + WS_XPROJ),
                                                 ws + WS_KW, ws + WS_OUTPRE, ws + WS_PART);

    finale_kernel<<<NPIX / 4, 256, 0, stream>>>(ws + WS_OUTPRE, ws + WS_PART,
                                                se1_w, se1_b, se2_w, se2_b,
                                                w_out, b_out, out);
}